// Round 1
// baseline (1439.560 us; speedup 1.0000x reference)
//
#include <hip/hip_runtime.h>
#include <hip/hip_bf16.h>
#include <math.h>

#define D_ 256
#define B_ 65536
#define C_ 1000

typedef _Float16 f16x8 __attribute__((ext_vector_type(8)));
typedef _Float16 f16x4 __attribute__((ext_vector_type(4)));
typedef float f32x4 __attribute__((ext_vector_type(4)));

// ---------------- kernel 1: cov = bc @ bc^T in fp64 ----------------
__global__ void cov_kernel(const float* __restrict__ bc, double* __restrict__ C64) {
  int i = blockIdx.x, j = threadIdx.x;
  const float* ri = bc + i * D_;
  const float* rj = bc + j * D_;
  double s = 0.0;
#pragma unroll 8
  for (int k = 0; k < D_; ++k) s += (double)ri[k] * (double)rj[k];
  C64[i * D_ + j] = s;
}

// ---------------- kernel 2: in-place Cholesky (lower), 1 block, 256 thr ----------------
__global__ void chol_kernel(double* __restrict__ A) {
  const int i = threadIdx.x;
  __shared__ double rowj[D_];
  __shared__ double diag;
  for (int j = 0; j < D_; ++j) {
    if (i < j) rowj[i] = A[j * D_ + i];
    __syncthreads();
    double s = 0.0;
    if (i >= j) {
      const double* Li = A + i * D_;
      for (int k = 0; k < j; ++k) s += Li[k] * rowj[k];
    }
    if (i == j) { double d = sqrt(A[j * D_ + j] - s); diag = d; A[j * D_ + j] = d; }
    __syncthreads();
    if (i > j) A[i * D_ + j] = (A[i * D_ + j] - s) / diag;
    __syncthreads();
  }
}

// ---------------- kernel 3: W = L^-1, one block (64 thr) per column ----------------
__global__ void inv_kernel(const double* __restrict__ L, double* __restrict__ Wcol) {
  const int c = blockIdx.x, l = threadIdx.x;
  __shared__ double w[D_];
  if (l == 0) w[c] = 1.0 / L[c * D_ + c];
  __syncthreads();
  for (int i = c + 1; i < D_; ++i) {
    const double* Li = L + i * D_;
    double s = 0.0;
    for (int k = c + l; k < i; k += 64) s += Li[k] * w[k];
#pragma unroll
    for (int d = 1; d < 64; d <<= 1) s += __shfl_xor(s, d, 64);
    if (l == 0) w[i] = -s / Li[i];
    __syncthreads();
  }
  for (int i = c + l; i < D_; i += 64) Wcol[c * D_ + i] = w[i];  // Wcol[c*D+i] = W[i][c]
}

// ---------------- kernel 4: cast to f16: Wb[i][k] row-major, WbT[k][i] ----------------
__global__ void convert_kernel(const double* __restrict__ Wcol,
                               _Float16* __restrict__ Wb, _Float16* __restrict__ WbT) {
  int i = blockIdx.x, k = threadIdx.x;
  float v = (k <= i) ? (float)Wcol[k * D_ + i] : 0.0f;
  _Float16 h = (_Float16)v;
  Wb[i * D_ + k] = h;
  WbT[k * D_ + i] = h;
}

// ---------------- kernel 5: signatures: sHat_un[c][i] = (W s_c)[i], rnS[c]=1/max(||.||,eps) ----------------
__global__ void sig_kernel(const float* __restrict__ S, const _Float16* __restrict__ WbT,
                           _Float16* __restrict__ sHat, float* __restrict__ rnS) {
  int c = blockIdx.x, i = threadIdx.x;
  __shared__ float srow[D_];
  __shared__ float wred[4];
  srow[i] = S[c * D_ + i];
  __syncthreads();
  float t = 0.f;
  for (int k = 0; k < D_; ++k) t += (float)WbT[k * D_ + i] * srow[k];
  float ss = t * t;
#pragma unroll
  for (int d = 1; d < 64; d <<= 1) ss += __shfl_xor(ss, d, 64);
  if ((i & 63) == 0) wred[i >> 6] = ss;
  __syncthreads();
  float tot = wred[0] + wred[1] + wred[2] + wred[3];
  sHat[c * D_ + i] = (_Float16)t;
  if (i == 0) rnS[c] = 1.0f / fmaxf(sqrtf(tot), 1e-12f);
}

// ---------------- kernel 6: xHat_un = (X - m) @ W^T (MFMA), rnX per row ----------------
__global__ __launch_bounds__(256) void xform_kernel(const float* __restrict__ X,
                                                    const float* __restrict__ means,
                                                    const _Float16* __restrict__ Wb,
                                                    _Float16* __restrict__ xHat,
                                                    float* __restrict__ rnX) {
  __shared__ __align__(16) _Float16 As[64 * D_];   // 32 KB, swizzled
  __shared__ __align__(16) _Float16 Bs[128 * D_];  // 64 KB, swizzled
  __shared__ float msh[D_];
  const int tid = threadIdx.x;
  const int rowbase = blockIdx.x * 64;
  msh[tid] = means[tid];
  __syncthreads();
  // stage A: (X - m) -> f16, 8B chunks
  for (int s = 0; s < 16; ++s) {
    int c = s * 256 + tid;
    int r = c >> 6, q = c & 63;
    const float4 xv = *(const float4*)(X + (size_t)(rowbase + r) * D_ + q * 4);
    f16x4 hv;
    hv[0] = (_Float16)(xv.x - msh[q * 4 + 0]);
    hv[1] = (_Float16)(xv.y - msh[q * 4 + 1]);
    hv[2] = (_Float16)(xv.z - msh[q * 4 + 2]);
    hv[3] = (_Float16)(xv.w - msh[q * 4 + 3]);
    int byte = (q * 8) ^ ((r & 7) << 4);
    *(f16x4*)((char*)(As + r * D_) + byte) = hv;
  }
  const int w = tid >> 6, l = tid & 63, lr = l & 15, lq = l >> 4;
  float ss[4] = {0.f, 0.f, 0.f, 0.f};
  for (int ch = 0; ch < 2; ++ch) {
    __syncthreads();
    for (int s = 0; s < 16; ++s) {
      int c = s * 256 + tid;
      int r = c >> 5, q = c & 31;
      uint4 v = *(const uint4*)(Wb + (size_t)(ch * 128 + r) * D_ + q * 8);
      int byte = (q * 16) ^ ((r & 7) << 4);
      *(uint4*)((char*)(Bs + r * D_) + byte) = v;
    }
    __syncthreads();
    f32x4 acc[8];
#pragma unroll
    for (int t = 0; t < 8; ++t) acc[t] = (f32x4){0.f, 0.f, 0.f, 0.f};
#pragma unroll
    for (int ks = 0; ks < 8; ++ks) {
      int arow = w * 16 + lr;
      int abyte = (ks * 64 + lq * 16) ^ ((arow & 7) << 4);
      f16x8 af = *(const f16x8*)((char*)(As + arow * D_) + abyte);
#pragma unroll
      for (int t = 0; t < 8; ++t) {
        int brow = t * 16 + lr;
        int bbyte = (ks * 64 + lq * 16) ^ ((brow & 7) << 4);
        f16x8 bf = *(const f16x8*)((char*)(Bs + brow * D_) + bbyte);
        acc[t] = __builtin_amdgcn_mfma_f32_16x16x32_f16(af, bf, acc[t], 0, 0, 0);
      }
    }
#pragma unroll
    for (int t = 0; t < 8; ++t) {
      int col = ch * 128 + t * 16 + lr;
#pragma unroll
      for (int j = 0; j < 4; ++j) {
        int row = rowbase + w * 16 + lq * 4 + j;
        float v = acc[t][j];
        ss[j] += v * v;
        xHat[(size_t)row * D_ + col] = (_Float16)v;
      }
    }
  }
#pragma unroll
  for (int d = 1; d < 16; d <<= 1) {
#pragma unroll
    for (int j = 0; j < 4; ++j) ss[j] += __shfl_xor(ss[j], d, 64);
  }
  if (lr == 0) {
#pragma unroll
    for (int j = 0; j < 4; ++j) {
      int row = rowbase + w * 16 + lq * 4 + j;
      rnX[row] = 1.0f / fmaxf(sqrtf(ss[j]), 1e-12f);
    }
  }
}

// ---------------- kernel 7: zero the loss accumulator ----------------
__global__ void zero_kernel(double* a) { *a = 0.0; }

// ---------------- kernel 8: main GEMM + fused logsumexp/loss ----------------
__global__ __launch_bounds__(256) void ace_kernel(const _Float16* __restrict__ xHat,
                                                  const _Float16* __restrict__ sHat,
                                                  const float* __restrict__ rnX,
                                                  const float* __restrict__ rnS,
                                                  const int* __restrict__ labels,
                                                  float* __restrict__ outACE,
                                                  double* __restrict__ acc_loss) {
  __shared__ __align__(16) _Float16 As[64 * D_];   // 32 KB
  __shared__ __align__(16) _Float16 Bs[128 * D_];  // 64 KB
  __shared__ float rnsh[1024];
  __shared__ float part[16];
  const int tid = threadIdx.x;
  const int rowbase = blockIdx.x * 64;
  for (int s = 0; s < 8; ++s) {
    int c = s * 256 + tid;
    int r = c >> 5, q = c & 31;
    uint4 v = *(const uint4*)(xHat + (size_t)(rowbase + r) * D_ + q * 8);
    int byte = (q * 16) ^ ((r & 7) << 4);
    *(uint4*)((char*)(As + r * D_) + byte) = v;
  }
  for (int s = tid; s < 1024; s += 256) rnsh[s] = (s < C_) ? rnS[s] : 0.0f;
  const int w = tid >> 6, l = tid & 63, lr = l & 15, lq = l >> 4;
  int lab[4]; float rx[4], m[4], ssum[4], num[4];
#pragma unroll
  for (int j = 0; j < 4; ++j) {
    int row = rowbase + w * 16 + lq * 4 + j;
    lab[j] = labels[row];
    rx[j] = rnX[row];
    m[j] = -INFINITY; ssum[j] = 0.f; num[j] = 0.f;
  }
  for (int ch = 0; ch < 8; ++ch) {
    __syncthreads();
    for (int s = 0; s < 16; ++s) {
      int c = s * 256 + tid;
      int r = c >> 5, q = c & 31;
      int gc = ch * 128 + r;
      uint4 v;
      if (gc < C_) v = *(const uint4*)(sHat + (size_t)gc * D_ + q * 8);
      else { v.x = 0u; v.y = 0u; v.z = 0u; v.w = 0u; }
      int byte = (q * 16) ^ ((r & 7) << 4);
      *(uint4*)((char*)(Bs + r * D_) + byte) = v;
    }
    __syncthreads();
    f32x4 acc[8];
#pragma unroll
    for (int t = 0; t < 8; ++t) acc[t] = (f32x4){0.f, 0.f, 0.f, 0.f};
#pragma unroll
    for (int ks = 0; ks < 8; ++ks) {
      int arow = w * 16 + lr;
      int abyte = (ks * 64 + lq * 16) ^ ((arow & 7) << 4);
      f16x8 af = *(const f16x8*)((char*)(As + arow * D_) + abyte);
#pragma unroll
      for (int t = 0; t < 8; ++t) {
        int brow = t * 16 + lr;
        int bbyte = (ks * 64 + lq * 16) ^ ((brow & 7) << 4);
        f16x8 bf = *(const f16x8*)((char*)(Bs + brow * D_) + bbyte);
        acc[t] = __builtin_amdgcn_mfma_f32_16x16x32_f16(af, bf, acc[t], 0, 0, 0);
      }
    }
#pragma unroll
    for (int t = 0; t < 8; ++t) {
      int col = ch * 128 + t * 16 + lr;
      if (col < C_) {
        float rs = rnsh[col];
#pragma unroll
        for (int j = 0; j < 4; ++j) {
          int row = rowbase + w * 16 + lq * 4 + j;
          float v = acc[t][j] * rx[j] * rs;
          outACE[(size_t)row * C_ + col] = v;
          if (v > m[j]) { ssum[j] = ssum[j] * __expf(m[j] - v) + 1.0f; m[j] = v; }
          else ssum[j] += __expf(v - m[j]);
          if (col == lab[j]) num[j] = v;
        }
      }
    }
  }
#pragma unroll
  for (int d2 = 1; d2 < 16; d2 <<= 1) {
#pragma unroll
    for (int j = 0; j < 4; ++j) {
      float mo = __shfl_xor(m[j], d2, 64);
      float so = __shfl_xor(ssum[j], d2, 64);
      float mn = fmaxf(m[j], mo);
      ssum[j] = ssum[j] * __expf(m[j] - mn) + so * __expf(mo - mn);
      m[j] = mn;
      num[j] += __shfl_xor(num[j], d2, 64);
    }
  }
  if (lr == 0) {
    float contrib = 0.f;
#pragma unroll
    for (int j = 0; j < 4; ++j) contrib += num[j] - (m[j] + __logf(ssum[j]));
    part[w * 4 + lq] = contrib;
  }
  __syncthreads();
  if (tid == 0) {
    float s = 0.f;
#pragma unroll
    for (int p2 = 0; p2 < 16; ++p2) s += part[p2];
    atomicAdd(acc_loss, (double)s);
  }
}

// ---------------- kernel 9: finalize loss ----------------
__global__ void fin_kernel(const double* a, float* out) {
  out[0] = (float)(-(*a) / (double)B_);
}

extern "C" void kernel_launch(void* const* d_in, const int* in_sizes, int n_in,
                              void* d_out, int out_size, void* d_ws, size_t ws_size,
                              hipStream_t stream) {
  const float* X      = (const float*)d_in[0];
  const int*   labels = (const int*)d_in[1];
  const float* S      = (const float*)d_in[2];
  const float* means  = (const float*)d_in[3];
  const float* bc     = (const float*)d_in[4];
  float* out = (float*)d_out;

  char* w = (char*)d_ws;
  double*    acc  = (double*)(w + 0);
  double*    C64  = (double*)(w + 256);          // 512 KB
  double*    Wcol = (double*)(w + 524544);       // 512 KB
  _Float16*  Wb   = (_Float16*)(w + 1048832);    // 128 KB
  _Float16*  WbT  = (_Float16*)(w + 1179904);    // 128 KB
  _Float16*  sHat = (_Float16*)(w + 1310976);    // 500 KB
  float*     rnS  = (float*)(w + 1822976);       // 4 KB
  float*     rnX  = (float*)(w + 1827072);       // 256 KB
  _Float16*  xHat = (_Float16*)(w + 2089216);    // 32 MB

  cov_kernel<<<256, 256, 0, stream>>>(bc, C64);
  chol_kernel<<<1, 256, 0, stream>>>(C64);
  inv_kernel<<<256, 64, 0, stream>>>(C64, Wcol);
  convert_kernel<<<256, 256, 0, stream>>>(Wcol, Wb, WbT);
  sig_kernel<<<1000, 256, 0, stream>>>(S, WbT, sHat, rnS);
  xform_kernel<<<1024, 256, 0, stream>>>(X, means, Wb, xHat, rnX);
  zero_kernel<<<1, 1, 0, stream>>>(acc);
  ace_kernel<<<1024, 256, 0, stream>>>(xHat, sHat, rnX, rnS, labels, out + 1, acc);
  fin_kernel<<<1, 1, 0, stream>>>(acc, out);
}

// Round 2
// 608.790 us; speedup vs baseline: 2.3646x; 2.3646x over previous
//
#include <hip/hip_runtime.h>
#include <hip/hip_bf16.h>
#include <math.h>

#define D_ 256
#define B_ 65536
#define C_ 1000

typedef _Float16 f16x8 __attribute__((ext_vector_type(8)));
typedef _Float16 f16x4 __attribute__((ext_vector_type(4)));
typedef float f32x4 __attribute__((ext_vector_type(4)));

// ---------------- kernel 1: cov = bc @ bc^T in fp64 ----------------
__global__ void cov_kernel(const float* __restrict__ bc, double* __restrict__ C64) {
  int i = blockIdx.x, j = threadIdx.x;
  const float* ri = bc + i * D_;
  const float* rj = bc + j * D_;
  double s = 0.0;
#pragma unroll 8
  for (int k = 0; k < D_; ++k) s += (double)ri[k] * (double)rj[k];
  C64[i * D_ + j] = s;
}

// ---------------- kernel 2: blocked right-looking Cholesky (lower), 1 block ----
// Panel width 32. Panel rows in registers (thread = row), factored panel staged
// to LDS (padded stride 33), rank-32 trailing update balanced over 256 threads.
__global__ __launch_bounds__(256) void chol_kernel(double* __restrict__ A) {
  const int tid = threadIdx.x;
  __shared__ double Lp[256][33];   // 67.6 KB: factored panel rows (abs row idx)
  __shared__ double diagd;
  __shared__ double rowv[32];

  for (int p = 0; p < 8; ++p) {
    const int j0 = p * 32;
    const int r = tid;
    double pr[32];
    if (r >= j0) {
#pragma unroll
      for (int k = 0; k < 32; ++k) pr[k] = A[(size_t)r * D_ + j0 + k];
    }
    // ---- factor 32 columns (rank-1 register updates) ----
    for (int j = 0; j < 32; ++j) {
      const int col = j0 + j;
      if (r == col) diagd = sqrt(pr[j]);
      __syncthreads();
      double lr = 0.0;
      if (r >= col) {
        lr = (r == col) ? diagd : pr[j] / diagd;
        pr[j] = lr;
        if (r < j0 + 32) rowv[r - j0] = lr;   // current column values at panel rows
      }
      __syncthreads();
      if (r > col) {
#pragma unroll
        for (int k = 0; k < 32; ++k)
          if (k > j) pr[k] -= lr * rowv[k];
      }
    }
    // ---- write back panel (lower part only) + stage full panel to LDS ----
    if (r >= j0) {
      const int kmax = (r - j0 < 31) ? (r - j0) : 31;
      for (int k = 0; k <= kmax; ++k) A[(size_t)r * D_ + j0 + k] = pr[k];
#pragma unroll
      for (int k = 0; k < 32; ++k) Lp[r][k] = pr[k];
    }
    __syncthreads();
    // ---- trailing update: A[rr][c] -= sum_k Lp[rr][k]*Lp[c][k], rr>=c>=j0+32 --
    const int t0 = j0 + 32;
    if (t0 < D_) {
      const int g = tid >> 5;        // column group 0..7
      const int lane = tid & 31;     // row lane
      for (int cb = t0; cb < D_; cb += 8) {
        const int c = cb + g;
        if (c < D_) {
          for (int rr = c + lane; rr < D_; rr += 32) {
            double s = 0.0;
#pragma unroll
            for (int k = 0; k < 32; ++k) s += Lp[rr][k] * Lp[c][k];
            A[(size_t)rr * D_ + c] -= s;
          }
        }
      }
    }
    __syncthreads();
  }
}

// ---------------- kernel 3: W = L^-1 column c, chunked forward substitution ----
__global__ __launch_bounds__(256) void inv_kernel(const double* __restrict__ L,
                                                  double* __restrict__ Wcol) {
  const int c = blockIdx.x;
  const int tid = threadIdx.x;
  __shared__ double w[D_];
  __shared__ double rdi[D_];
  __shared__ double rhs[32];
  __shared__ double Ldd[32][33];
  w[tid] = 0.0;
  rdi[tid] = 1.0 / L[(size_t)tid * D_ + tid];
  __syncthreads();
  const int q0 = c >> 5;
  for (int q = q0; q < 8; ++q) {
    const int i0 = q * 32;
    const int ii = tid >> 3, s = tid & 7;
    const int i = i0 + ii;
    // rhs[ii] = delta(i,c) - sum_{k in [c, i0)} L[i][k] * w[k]   (8 lanes per row)
    double part = 0.0;
    for (int k = c + s; k < i0; k += 8) part += L[(size_t)i * D_ + k] * w[k];
    part += __shfl_xor(part, 1, 64);
    part += __shfl_xor(part, 2, 64);
    part += __shfl_xor(part, 4, 64);
    if (s == 0) rhs[ii] = ((i == c) ? 1.0 : 0.0) - part;
    // stage diag block
    for (int e = tid; e < 32 * 32; e += 256) {
      int rr = e >> 5, cc = e & 31;
      Ldd[rr][cc] = L[(size_t)(i0 + rr) * D_ + i0 + cc];
    }
    __syncthreads();
    // serial in-chunk solve, lanes 0..31 of wave 0
    if (tid < 32) {
      double x = rhs[tid];
      double v = 0.0;
      for (int j = 0; j < 32; ++j) {
        double xj = __shfl(x, j, 64);
        double wj = xj * rdi[i0 + j];
        if (tid == j) v = wj;
        if (tid > j) x -= Ldd[tid][j] * wj;
      }
      w[i0 + tid] = v;
      Wcol[(size_t)c * D_ + i0 + tid] = v;   // Wcol[c*D+i] = W[i][c]
    }
    __syncthreads();
  }
}

// ---------------- kernel 4: cast to f16: Wb[i][k] row-major, WbT[k][i] ----------------
__global__ void convert_kernel(const double* __restrict__ Wcol,
                               _Float16* __restrict__ Wb, _Float16* __restrict__ WbT) {
  int i = blockIdx.x, k = threadIdx.x;
  float v = (k <= i) ? (float)Wcol[k * D_ + i] : 0.0f;
  _Float16 h = (_Float16)v;
  Wb[i * D_ + k] = h;
  WbT[k * D_ + i] = h;
}

// ---------------- kernel 5: signatures: sHat_un[c][i] = (W s_c)[i], rnS[c]=1/max(||.||,eps) ----------------
__global__ void sig_kernel(const float* __restrict__ S, const _Float16* __restrict__ WbT,
                           _Float16* __restrict__ sHat, float* __restrict__ rnS) {
  int c = blockIdx.x, i = threadIdx.x;
  __shared__ float srow[D_];
  __shared__ float wred[4];
  srow[i] = S[c * D_ + i];
  __syncthreads();
  float t = 0.f;
  for (int k = 0; k < D_; ++k) t += (float)WbT[k * D_ + i] * srow[k];
  float ss = t * t;
#pragma unroll
  for (int d = 1; d < 64; d <<= 1) ss += __shfl_xor(ss, d, 64);
  if ((i & 63) == 0) wred[i >> 6] = ss;
  __syncthreads();
  float tot = wred[0] + wred[1] + wred[2] + wred[3];
  sHat[c * D_ + i] = (_Float16)t;
  if (i == 0) rnS[c] = 1.0f / fmaxf(sqrtf(tot), 1e-12f);
}

// ---------------- kernel 6: xHat_un = (X - m) @ W^T (MFMA), rnX per row ----------------
__global__ __launch_bounds__(256) void xform_kernel(const float* __restrict__ X,
                                                    const float* __restrict__ means,
                                                    const _Float16* __restrict__ Wb,
                                                    _Float16* __restrict__ xHat,
                                                    float* __restrict__ rnX) {
  __shared__ __align__(16) _Float16 As[64 * D_];   // 32 KB, swizzled
  __shared__ __align__(16) _Float16 Bs[128 * D_];  // 64 KB, swizzled
  __shared__ float msh[D_];
  const int tid = threadIdx.x;
  const int rowbase = blockIdx.x * 64;
  msh[tid] = means[tid];
  __syncthreads();
  // stage A: (X - m) -> f16, 8B chunks
  for (int s = 0; s < 16; ++s) {
    int c = s * 256 + tid;
    int r = c >> 6, q = c & 63;
    const float4 xv = *(const float4*)(X + (size_t)(rowbase + r) * D_ + q * 4);
    f16x4 hv;
    hv[0] = (_Float16)(xv.x - msh[q * 4 + 0]);
    hv[1] = (_Float16)(xv.y - msh[q * 4 + 1]);
    hv[2] = (_Float16)(xv.z - msh[q * 4 + 2]);
    hv[3] = (_Float16)(xv.w - msh[q * 4 + 3]);
    int byte = (q * 8) ^ ((r & 7) << 4);
    *(f16x4*)((char*)(As + r * D_) + byte) = hv;
  }
  const int w = tid >> 6, l = tid & 63, lr = l & 15, lq = l >> 4;
  float ss[4] = {0.f, 0.f, 0.f, 0.f};
  for (int ch = 0; ch < 2; ++ch) {
    __syncthreads();
    for (int s = 0; s < 16; ++s) {
      int c = s * 256 + tid;
      int r = c >> 5, q = c & 31;
      uint4 v = *(const uint4*)(Wb + (size_t)(ch * 128 + r) * D_ + q * 8);
      int byte = (q * 16) ^ ((r & 7) << 4);
      *(uint4*)((char*)(Bs + r * D_) + byte) = v;
    }
    __syncthreads();
    f32x4 acc[8];
#pragma unroll
    for (int t = 0; t < 8; ++t) acc[t] = (f32x4){0.f, 0.f, 0.f, 0.f};
#pragma unroll
    for (int ks = 0; ks < 8; ++ks) {
      int arow = w * 16 + lr;
      int abyte = (ks * 64 + lq * 16) ^ ((arow & 7) << 4);
      f16x8 af = *(const f16x8*)((char*)(As + arow * D_) + abyte);
#pragma unroll
      for (int t = 0; t < 8; ++t) {
        int brow = t * 16 + lr;
        int bbyte = (ks * 64 + lq * 16) ^ ((brow & 7) << 4);
        f16x8 bf = *(const f16x8*)((char*)(Bs + brow * D_) + bbyte);
        acc[t] = __builtin_amdgcn_mfma_f32_16x16x32_f16(af, bf, acc[t], 0, 0, 0);
      }
    }
#pragma unroll
    for (int t = 0; t < 8; ++t) {
      int col = ch * 128 + t * 16 + lr;
#pragma unroll
      for (int j = 0; j < 4; ++j) {
        int row = rowbase + w * 16 + lq * 4 + j;
        float v = acc[t][j];
        ss[j] += v * v;
        xHat[(size_t)row * D_ + col] = (_Float16)v;
      }
    }
  }
#pragma unroll
  for (int d = 1; d < 16; d <<= 1) {
#pragma unroll
    for (int j = 0; j < 4; ++j) ss[j] += __shfl_xor(ss[j], d, 64);
  }
  if (lr == 0) {
#pragma unroll
    for (int j = 0; j < 4; ++j) {
      int row = rowbase + w * 16 + lq * 4 + j;
      rnX[row] = 1.0f / fmaxf(sqrtf(ss[j]), 1e-12f);
    }
  }
}

// ---------------- kernel 7: zero the loss accumulator ----------------
__global__ void zero_kernel(double* a) { *a = 0.0; }

// ---------------- kernel 8: main GEMM + fused logsumexp/loss ----------------
__global__ __launch_bounds__(256) void ace_kernel(const _Float16* __restrict__ xHat,
                                                  const _Float16* __restrict__ sHat,
                                                  const float* __restrict__ rnX,
                                                  const float* __restrict__ rnS,
                                                  const int* __restrict__ labels,
                                                  float* __restrict__ outACE,
                                                  double* __restrict__ acc_loss) {
  __shared__ __align__(16) _Float16 As[64 * D_];   // 32 KB
  __shared__ __align__(16) _Float16 Bs[128 * D_];  // 64 KB
  __shared__ float rnsh[1024];
  __shared__ float part[16];
  const int tid = threadIdx.x;
  const int rowbase = blockIdx.x * 64;
  for (int s = 0; s < 8; ++s) {
    int c = s * 256 + tid;
    int r = c >> 5, q = c & 31;
    uint4 v = *(const uint4*)(xHat + (size_t)(rowbase + r) * D_ + q * 8);
    int byte = (q * 16) ^ ((r & 7) << 4);
    *(uint4*)((char*)(As + r * D_) + byte) = v;
  }
  for (int s = tid; s < 1024; s += 256) rnsh[s] = (s < C_) ? rnS[s] : 0.0f;
  const int w = tid >> 6, l = tid & 63, lr = l & 15, lq = l >> 4;
  int lab[4]; float rx[4], m[4], ssum[4], num[4];
#pragma unroll
  for (int j = 0; j < 4; ++j) {
    int row = rowbase + w * 16 + lq * 4 + j;
    lab[j] = labels[row];
    rx[j] = rnX[row];
    m[j] = -INFINITY; ssum[j] = 0.f; num[j] = 0.f;
  }
  for (int ch = 0; ch < 8; ++ch) {
    __syncthreads();
    for (int s = 0; s < 16; ++s) {
      int c = s * 256 + tid;
      int r = c >> 5, q = c & 31;
      int gc = ch * 128 + r;
      uint4 v;
      if (gc < C_) v = *(const uint4*)(sHat + (size_t)gc * D_ + q * 8);
      else { v.x = 0u; v.y = 0u; v.z = 0u; v.w = 0u; }
      int byte = (q * 16) ^ ((r & 7) << 4);
      *(uint4*)((char*)(Bs + r * D_) + byte) = v;
    }
    __syncthreads();
    f32x4 acc[8];
#pragma unroll
    for (int t = 0; t < 8; ++t) acc[t] = (f32x4){0.f, 0.f, 0.f, 0.f};
#pragma unroll
    for (int ks = 0; ks < 8; ++ks) {
      int arow = w * 16 + lr;
      int abyte = (ks * 64 + lq * 16) ^ ((arow & 7) << 4);
      f16x8 af = *(const f16x8*)((char*)(As + arow * D_) + abyte);
#pragma unroll
      for (int t = 0; t < 8; ++t) {
        int brow = t * 16 + lr;
        int bbyte = (ks * 64 + lq * 16) ^ ((brow & 7) << 4);
        f16x8 bf = *(const f16x8*)((char*)(Bs + brow * D_) + bbyte);
        acc[t] = __builtin_amdgcn_mfma_f32_16x16x32_f16(af, bf, acc[t], 0, 0, 0);
      }
    }
#pragma unroll
    for (int t = 0; t < 8; ++t) {
      int col = ch * 128 + t * 16 + lr;
      if (col < C_) {
        float rs = rnsh[col];
#pragma unroll
        for (int j = 0; j < 4; ++j) {
          int row = rowbase + w * 16 + lq * 4 + j;
          float v = acc[t][j] * rx[j] * rs;
          outACE[(size_t)row * C_ + col] = v;
          if (v > m[j]) { ssum[j] = ssum[j] * __expf(m[j] - v) + 1.0f; m[j] = v; }
          else ssum[j] += __expf(v - m[j]);
          if (col == lab[j]) num[j] = v;
        }
      }
    }
  }
#pragma unroll
  for (int d2 = 1; d2 < 16; d2 <<= 1) {
#pragma unroll
    for (int j = 0; j < 4; ++j) {
      float mo = __shfl_xor(m[j], d2, 64);
      float so = __shfl_xor(ssum[j], d2, 64);
      float mn = fmaxf(m[j], mo);
      ssum[j] = ssum[j] * __expf(m[j] - mn) + so * __expf(mo - mn);
      m[j] = mn;
      num[j] += __shfl_xor(num[j], d2, 64);
    }
  }
  if (lr == 0) {
    float contrib = 0.f;
#pragma unroll
    for (int j = 0; j < 4; ++j) contrib += num[j] - (m[j] + __logf(ssum[j]));
    part[w * 4 + lq] = contrib;
  }
  __syncthreads();
  if (tid == 0) {
    float s = 0.f;
#pragma unroll
    for (int p2 = 0; p2 < 16; ++p2) s += part[p2];
    atomicAdd(acc_loss, (double)s);
  }
}

// ---------------- kernel 9: finalize loss ----------------
__global__ void fin_kernel(const double* a, float* out) {
  out[0] = (float)(-(*a) / (double)B_);
}

extern "C" void kernel_launch(void* const* d_in, const int* in_sizes, int n_in,
                              void* d_out, int out_size, void* d_ws, size_t ws_size,
                              hipStream_t stream) {
  const float* X      = (const float*)d_in[0];
  const int*   labels = (const int*)d_in[1];
  const float* S      = (const float*)d_in[2];
  const float* means  = (const float*)d_in[3];
  const float* bc     = (const float*)d_in[4];
  float* out = (float*)d_out;

  char* w = (char*)d_ws;
  double*    acc  = (double*)(w + 0);
  double*    C64  = (double*)(w + 256);          // 512 KB
  double*    Wcol = (double*)(w + 524544);       // 512 KB
  _Float16*  Wb   = (_Float16*)(w + 1048832);    // 128 KB
  _Float16*  WbT  = (_Float16*)(w + 1179904);    // 128 KB
  _Float16*  sHat = (_Float16*)(w + 1310976);    // 500 KB
  float*     rnS  = (float*)(w + 1822976);       // 4 KB
  float*     rnX  = (float*)(w + 1827072);       // 256 KB
  _Float16*  xHat = (_Float16*)(w + 2089216);    // 32 MB

  cov_kernel<<<256, 256, 0, stream>>>(bc, C64);
  chol_kernel<<<1, 256, 0, stream>>>(C64);
  inv_kernel<<<256, 64 * 4, 0, stream>>>(C64, Wcol);
  convert_kernel<<<256, 256, 0, stream>>>(Wcol, Wb, WbT);
  sig_kernel<<<1000, 256, 0, stream>>>(S, WbT, sHat, rnS);
  xform_kernel<<<1024, 256, 0, stream>>>(X, means, Wb, xHat, rnX);
  zero_kernel<<<1, 1, 0, stream>>>(acc);
  ace_kernel<<<1024, 256, 0, stream>>>(xHat, sHat, rnX, rnS, labels, out + 1, acc);
  fin_kernel<<<1, 1, 0, stream>>>(acc, out);
}

// Round 3
// 458.427 us; speedup vs baseline: 3.1402x; 1.3280x over previous
//
#include <hip/hip_runtime.h>
#include <hip/hip_bf16.h>
#include <math.h>

#define D_ 256
#define B_ 65536
#define C_ 1000

typedef _Float16 f16x8 __attribute__((ext_vector_type(8)));
typedef _Float16 f16x4 __attribute__((ext_vector_type(4)));
typedef float f32x4 __attribute__((ext_vector_type(4)));

// ---------------- kernel 0: transpose bc (256x256 f32) + zero loss acc ----------------
__global__ void transpose_kernel(const float* __restrict__ in, float* __restrict__ out,
                                 double* __restrict__ acc) {
  __shared__ float t[32][33];
  if (blockIdx.x == 0 && threadIdx.x == 0) *acc = 0.0;
  const int bx = blockIdx.x & 7, by = blockIdx.x >> 3;
  const int lx = threadIdx.x & 31, ly = threadIdx.x >> 5;  // 32 x 8
#pragma unroll
  for (int s = 0; s < 4; ++s) {
    int r = by * 32 + ly + s * 8;
    t[ly + s * 8][lx] = in[r * 256 + bx * 32 + lx];
  }
  __syncthreads();
#pragma unroll
  for (int s = 0; s < 4; ++s) {
    int r = bx * 32 + ly + s * 8;
    out[r * 256 + by * 32 + lx] = t[lx][ly + s * 8];
  }
}

// ---------------- kernel 1: cov = bc @ bc^T in fp64 (coalesced via bcT) ----------------
__global__ void cov_kernel(const float* __restrict__ bc, const float* __restrict__ bcT,
                           double* __restrict__ C64) {
  const int i = blockIdx.x, j = threadIdx.x;
  __shared__ float ri[D_];
  ri[j] = bc[i * D_ + j];
  __syncthreads();
  double s = 0.0;
#pragma unroll 8
  for (int k = 0; k < D_; ++k) s += (double)ri[k] * (double)bcT[k * D_ + j];
  C64[i * D_ + j] = s;
}

// ---------------- kernel 2a: factor panel p (64 cols), rows in registers ----------------
// Fully unrolled so all pr[] indices are compile-time (rule #20: no scratch).
__global__ __launch_bounds__(256, 1) void chol_panel(double* __restrict__ A, int p) {
  const int j0 = p * 64;
  const int r = threadIdx.x;
  __shared__ double rowv[64];
  __shared__ double dinv;
  double pr[64];
  const bool act = (r >= j0);
  if (act) {
#pragma unroll
    for (int k = 0; k < 64; ++k) pr[k] = A[(size_t)r * D_ + j0 + k];
  }
#pragma unroll
  for (int j = 0; j < 64; ++j) {
    const int col = j0 + j;
    if (r == col) { double d = sqrt(pr[j]); pr[j] = d; dinv = 1.0 / d; }
    __syncthreads();
    if (r > col) {
      double lr = pr[j] * dinv;
      pr[j] = lr;
      if (r < j0 + 64) rowv[r - j0] = lr;
    }
    __syncthreads();
    if (r > col) {
      const double lr = pr[j];
#pragma unroll
      for (int k = j + 1; k < 64; ++k) pr[k] -= lr * rowv[k];
    }
  }
  if (act) {
    const int kmax = (r - j0 < 63) ? (r - j0) : 63;
#pragma unroll
    for (int k = 0; k < 64; ++k)
      if (k <= kmax) A[(size_t)r * D_ + j0 + k] = pr[k];
  }
}

// ---------------- kernel 2b: trailing update for panel p, one block per 64x64 tile ----
__global__ __launch_bounds__(256) void chol_trail(double* __restrict__ A, int p) {
  const int j0 = p * 64;
  const int t0 = j0 + 64;
  int b = blockIdx.x, I = 0;
  while (b >= I + 1) { b -= I + 1; ++I; }   // lower tile pair (I,J), J<=I
  const int J = b;
  const int r0 = t0 + I * 64, c0 = t0 + J * 64;
  __shared__ double LR[64][67];
  __shared__ double LC[64][67];
  const int tid = threadIdx.x;
  for (int e = tid; e < 64 * 64; e += 256) {
    int rr = e >> 6, cc = e & 63;
    LR[rr][cc] = A[(size_t)(r0 + rr) * D_ + j0 + cc];
    LC[rr][cc] = A[(size_t)(c0 + rr) * D_ + j0 + cc];
  }
  __syncthreads();
  const int tx = tid & 15, ty = tid >> 4;
  double acc[4][4];
#pragma unroll
  for (int i = 0; i < 4; ++i)
#pragma unroll
    for (int j = 0; j < 4; ++j) acc[i][j] = 0.0;
#pragma unroll 4
  for (int k = 0; k < 64; ++k) {
    double a_[4], b_[4];
#pragma unroll
    for (int i = 0; i < 4; ++i) a_[i] = LR[ty + 16 * i][k];
#pragma unroll
    for (int j = 0; j < 4; ++j) b_[j] = LC[tx + 16 * j][k];
#pragma unroll
    for (int i = 0; i < 4; ++i)
#pragma unroll
      for (int j = 0; j < 4; ++j) acc[i][j] += a_[i] * b_[j];
  }
#pragma unroll
  for (int i = 0; i < 4; ++i) {
    const int grow = r0 + ty + 16 * i;
#pragma unroll
    for (int j = 0; j < 4; ++j) {
      const int gcol = c0 + tx + 16 * j;
      A[(size_t)grow * D_ + gcol] -= acc[i][j];   // full tile (keeps diag tiles symmetric)
    }
  }
}

// ---------------- kernel 3: W = L^-1 column c, chunked forward substitution ----
__global__ __launch_bounds__(256) void inv_kernel(const double* __restrict__ L,
                                                  double* __restrict__ Wcol) {
  const int c = blockIdx.x;
  const int tid = threadIdx.x;
  __shared__ double w[D_];
  __shared__ double rdi[D_];
  __shared__ double rhs[32];
  __shared__ double Ldd[32][33];
  w[tid] = 0.0;
  rdi[tid] = 1.0 / L[(size_t)tid * D_ + tid];
  __syncthreads();
  const int q0 = c >> 5;
  for (int q = q0; q < 8; ++q) {
    const int i0 = q * 32;
    const int ii = tid >> 3, s = tid & 7;
    const int i = i0 + ii;
    double part = 0.0;
    for (int k = c + s; k < i0; k += 8) part += L[(size_t)i * D_ + k] * w[k];
    part += __shfl_xor(part, 1, 64);
    part += __shfl_xor(part, 2, 64);
    part += __shfl_xor(part, 4, 64);
    if (s == 0) rhs[ii] = ((i == c) ? 1.0 : 0.0) - part;
    for (int e = tid; e < 32 * 32; e += 256) {
      int rr = e >> 5, cc = e & 31;
      Ldd[rr][cc] = L[(size_t)(i0 + rr) * D_ + i0 + cc];
    }
    __syncthreads();
    if (tid < 32) {
      double x = rhs[tid];
      double v = 0.0;
      for (int j = 0; j < 32; ++j) {
        double xj = __shfl(x, j, 64);
        double wj = xj * rdi[i0 + j];
        if (tid == j) v = wj;
        if (tid > j) x -= Ldd[tid][j] * wj;
      }
      w[i0 + tid] = v;
      Wcol[(size_t)c * D_ + i0 + tid] = v;   // Wcol[c*D+i] = W[i][c]
    }
    __syncthreads();
  }
}

// ---------------- kernel 4: cast to f16 (block = k, thread = i: coalesced reads) -------
__global__ void convert_kernel(const double* __restrict__ Wcol,
                               _Float16* __restrict__ Wb, _Float16* __restrict__ WbT) {
  int k = blockIdx.x, i = threadIdx.x;
  float v = (k <= i) ? (float)Wcol[k * D_ + i] : 0.0f;
  _Float16 h = (_Float16)v;
  Wb[i * D_ + k] = h;
  WbT[k * D_ + i] = h;
}

// ---------------- kernel 5: signatures ----------------
__global__ void sig_kernel(const float* __restrict__ S, const _Float16* __restrict__ WbT,
                           _Float16* __restrict__ sHat, float* __restrict__ rnS) {
  int c = blockIdx.x, i = threadIdx.x;
  __shared__ float srow[D_];
  __shared__ float wred[4];
  srow[i] = S[c * D_ + i];
  __syncthreads();
  float t = 0.f;
  for (int k = 0; k < D_; ++k) t += (float)WbT[k * D_ + i] * srow[k];
  float ss = t * t;
#pragma unroll
  for (int d = 1; d < 64; d <<= 1) ss += __shfl_xor(ss, d, 64);
  if ((i & 63) == 0) wred[i >> 6] = ss;
  __syncthreads();
  float tot = wred[0] + wred[1] + wred[2] + wred[3];
  sHat[c * D_ + i] = (_Float16)t;
  if (i == 0) rnS[c] = 1.0f / fmaxf(sqrtf(tot), 1e-12f);
}

// ---------------- kernel 6: xHat_un = (X - m) @ W^T (MFMA), rnX per row ----------------
__global__ __launch_bounds__(256) void xform_kernel(const float* __restrict__ X,
                                                    const float* __restrict__ means,
                                                    const _Float16* __restrict__ Wb,
                                                    _Float16* __restrict__ xHat,
                                                    float* __restrict__ rnX) {
  __shared__ __align__(16) _Float16 As[64 * D_];   // 32 KB, swizzled
  __shared__ __align__(16) _Float16 Bs[128 * D_];  // 64 KB, swizzled
  __shared__ float msh[D_];
  const int tid = threadIdx.x;
  const int rowbase = blockIdx.x * 64;
  msh[tid] = means[tid];
  __syncthreads();
  for (int s = 0; s < 16; ++s) {
    int c = s * 256 + tid;
    int r = c >> 6, q = c & 63;
    const float4 xv = *(const float4*)(X + (size_t)(rowbase + r) * D_ + q * 4);
    f16x4 hv;
    hv[0] = (_Float16)(xv.x - msh[q * 4 + 0]);
    hv[1] = (_Float16)(xv.y - msh[q * 4 + 1]);
    hv[2] = (_Float16)(xv.z - msh[q * 4 + 2]);
    hv[3] = (_Float16)(xv.w - msh[q * 4 + 3]);
    int byte = (q * 8) ^ ((r & 7) << 4);
    *(f16x4*)((char*)(As + r * D_) + byte) = hv;
  }
  const int w = tid >> 6, l = tid & 63, lr = l & 15, lq = l >> 4;
  float ss[4] = {0.f, 0.f, 0.f, 0.f};
  for (int ch = 0; ch < 2; ++ch) {
    __syncthreads();
    for (int s = 0; s < 16; ++s) {
      int c = s * 256 + tid;
      int r = c >> 5, q = c & 31;
      uint4 v = *(const uint4*)(Wb + (size_t)(ch * 128 + r) * D_ + q * 8);
      int byte = (q * 16) ^ ((r & 7) << 4);
      *(uint4*)((char*)(Bs + r * D_) + byte) = v;
    }
    __syncthreads();
    f32x4 acc[8];
#pragma unroll
    for (int t = 0; t < 8; ++t) acc[t] = (f32x4){0.f, 0.f, 0.f, 0.f};
#pragma unroll
    for (int ks = 0; ks < 8; ++ks) {
      int arow = w * 16 + lr;
      int abyte = (ks * 64 + lq * 16) ^ ((arow & 7) << 4);
      f16x8 af = *(const f16x8*)((char*)(As + arow * D_) + abyte);
#pragma unroll
      for (int t = 0; t < 8; ++t) {
        int brow = t * 16 + lr;
        int bbyte = (ks * 64 + lq * 16) ^ ((brow & 7) << 4);
        f16x8 bf = *(const f16x8*)((char*)(Bs + brow * D_) + bbyte);
        acc[t] = __builtin_amdgcn_mfma_f32_16x16x32_f16(af, bf, acc[t], 0, 0, 0);
      }
    }
#pragma unroll
    for (int t = 0; t < 8; ++t) {
      int col = ch * 128 + t * 16 + lr;
#pragma unroll
      for (int j = 0; j < 4; ++j) {
        int row = rowbase + w * 16 + lq * 4 + j;
        float v = acc[t][j];
        ss[j] += v * v;
        xHat[(size_t)row * D_ + col] = (_Float16)v;
      }
    }
  }
#pragma unroll
  for (int d = 1; d < 16; d <<= 1) {
#pragma unroll
    for (int j = 0; j < 4; ++j) ss[j] += __shfl_xor(ss[j], d, 64);
  }
  if (lr == 0) {
#pragma unroll
    for (int j = 0; j < 4; ++j) {
      int row = rowbase + w * 16 + lq * 4 + j;
      rnX[row] = 1.0f / fmaxf(sqrtf(ss[j]), 1e-12f);
    }
  }
}

// ---------------- kernel 8: main GEMM + fused logsumexp/loss ----------------
__global__ __launch_bounds__(256) void ace_kernel(const _Float16* __restrict__ xHat,
                                                  const _Float16* __restrict__ sHat,
                                                  const float* __restrict__ rnX,
                                                  const float* __restrict__ rnS,
                                                  const int* __restrict__ labels,
                                                  float* __restrict__ outACE,
                                                  double* __restrict__ acc_loss) {
  __shared__ __align__(16) _Float16 As[64 * D_];   // 32 KB
  __shared__ __align__(16) _Float16 Bs[128 * D_];  // 64 KB
  __shared__ float rnsh[1024];
  __shared__ float part[16];
  const int tid = threadIdx.x;
  const int rowbase = blockIdx.x * 64;
  for (int s = 0; s < 8; ++s) {
    int c = s * 256 + tid;
    int r = c >> 5, q = c & 31;
    uint4 v = *(const uint4*)(xHat + (size_t)(rowbase + r) * D_ + q * 8);
    int byte = (q * 16) ^ ((r & 7) << 4);
    *(uint4*)((char*)(As + r * D_) + byte) = v;
  }
  for (int s = tid; s < 1024; s += 256) rnsh[s] = (s < C_) ? rnS[s] : 0.0f;
  const int w = tid >> 6, l = tid & 63, lr = l & 15, lq = l >> 4;
  int lab[4]; float rx[4], m[4], ssum[4], num[4];
#pragma unroll
  for (int j = 0; j < 4; ++j) {
    int row = rowbase + w * 16 + lq * 4 + j;
    lab[j] = labels[row];
    rx[j] = rnX[row];
    m[j] = -INFINITY; ssum[j] = 0.f; num[j] = 0.f;
  }
  for (int ch = 0; ch < 8; ++ch) {
    __syncthreads();
    for (int s = 0; s < 16; ++s) {
      int c = s * 256 + tid;
      int r = c >> 5, q = c & 31;
      int gc = ch * 128 + r;
      uint4 v;
      if (gc < C_) v = *(const uint4*)(sHat + (size_t)gc * D_ + q * 8);
      else { v.x = 0u; v.y = 0u; v.z = 0u; v.w = 0u; }
      int byte = (q * 16) ^ ((r & 7) << 4);
      *(uint4*)((char*)(Bs + r * D_) + byte) = v;
    }
    __syncthreads();
    f32x4 acc[8];
#pragma unroll
    for (int t = 0; t < 8; ++t) acc[t] = (f32x4){0.f, 0.f, 0.f, 0.f};
#pragma unroll
    for (int ks = 0; ks < 8; ++ks) {
      int arow = w * 16 + lr;
      int abyte = (ks * 64 + lq * 16) ^ ((arow & 7) << 4);
      f16x8 af = *(const f16x8*)((char*)(As + arow * D_) + abyte);
#pragma unroll
      for (int t = 0; t < 8; ++t) {
        int brow = t * 16 + lr;
        int bbyte = (ks * 64 + lq * 16) ^ ((brow & 7) << 4);
        f16x8 bf = *(const f16x8*)((char*)(Bs + brow * D_) + bbyte);
        acc[t] = __builtin_amdgcn_mfma_f32_16x16x32_f16(af, bf, acc[t], 0, 0, 0);
      }
    }
#pragma unroll
    for (int t = 0; t < 8; ++t) {
      int col = ch * 128 + t * 16 + lr;
      if (col < C_) {
        float rs = rnsh[col];
#pragma unroll
        for (int j = 0; j < 4; ++j) {
          int row = rowbase + w * 16 + lq * 4 + j;
          float v = acc[t][j] * rx[j] * rs;
          outACE[(size_t)row * C_ + col] = v;
          if (v > m[j]) { ssum[j] = ssum[j] * __expf(m[j] - v) + 1.0f; m[j] = v; }
          else ssum[j] += __expf(v - m[j]);
          if (col == lab[j]) num[j] = v;
        }
      }
    }
  }
#pragma unroll
  for (int d2 = 1; d2 < 16; d2 <<= 1) {
#pragma unroll
    for (int j = 0; j < 4; ++j) {
      float mo = __shfl_xor(m[j], d2, 64);
      float so = __shfl_xor(ssum[j], d2, 64);
      float mn = fmaxf(m[j], mo);
      ssum[j] = ssum[j] * __expf(m[j] - mn) + so * __expf(mo - mn);
      m[j] = mn;
      num[j] += __shfl_xor(num[j], d2, 64);
    }
  }
  if (lr == 0) {
    float contrib = 0.f;
#pragma unroll
    for (int j = 0; j < 4; ++j) contrib += num[j] - (m[j] + __logf(ssum[j]));
    part[w * 4 + lq] = contrib;
  }
  __syncthreads();
  if (tid == 0) {
    float s = 0.f;
#pragma unroll
    for (int p2 = 0; p2 < 16; ++p2) s += part[p2];
    atomicAdd(acc_loss, (double)s);
  }
}

// ---------------- kernel 9: finalize loss ----------------
__global__ void fin_kernel(const double* a, float* out) {
  out[0] = (float)(-(*a) / (double)B_);
}

extern "C" void kernel_launch(void* const* d_in, const int* in_sizes, int n_in,
                              void* d_out, int out_size, void* d_ws, size_t ws_size,
                              hipStream_t stream) {
  const float* X      = (const float*)d_in[0];
  const int*   labels = (const int*)d_in[1];
  const float* S      = (const float*)d_in[2];
  const float* means  = (const float*)d_in[3];
  const float* bc     = (const float*)d_in[4];
  float* out = (float*)d_out;

  char* w = (char*)d_ws;
  double*    acc  = (double*)(w + 0);
  double*    C64  = (double*)(w + 256);          // 512 KB
  double*    Wcol = (double*)(w + 524544);       // 512 KB
  _Float16*  Wb   = (_Float16*)(w + 1048832);    // 128 KB
  _Float16*  WbT  = (_Float16*)(w + 1179904);    // 128 KB
  _Float16*  sHat = (_Float16*)(w + 1310976);    // 500 KB
  float*     rnS  = (float*)(w + 1822976);       // 4 KB
  float*     rnX  = (float*)(w + 1827072);       // 256 KB
  _Float16*  xHat = (_Float16*)(w + 2089216);    // 32 MB
  float*     bcT  = (float*)(w + 2089216);       // aliases xHat (used before xform)

  transpose_kernel<<<64, 256, 0, stream>>>(bc, bcT, acc);
  cov_kernel<<<256, 256, 0, stream>>>(bc, bcT, C64);
  for (int p = 0; p < 4; ++p) {
    chol_panel<<<1, 256, 0, stream>>>(C64, p);
    int nt = 3 - p;
    if (nt > 0) chol_trail<<<nt * (nt + 1) / 2, 256, 0, stream>>>(C64, p);
  }
  inv_kernel<<<256, 256, 0, stream>>>(C64, Wcol);
  convert_kernel<<<256, 256, 0, stream>>>(Wcol, Wb, WbT);
  sig_kernel<<<1000, 256, 0, stream>>>(S, WbT, sHat, rnS);
  xform_kernel<<<1024, 256, 0, stream>>>(X, means, Wb, xHat, rnX);
  ace_kernel<<<1024, 256, 0, stream>>>(xHat, sHat, rnX, rnS, labels, out + 1, acc);
  fin_kernel<<<1, 1, 0, stream>>>(acc, out);
}